// Round 5
// baseline (845.007 us; speedup 1.0000x reference)
//
#include <hip/hip_runtime.h>

// MergedEmbeddingBag forward: sum-pool, T tables merged.
// weights: [T, N, D] f32, indices: [T, TOTAL] i32, offsets: [T, B] i32
// out: [T, B, D] f32
//
// Strategy: row-range partitioned gather. Each thread holds its bag's 20
// indices in registers and sweeps P row-ranges; range size (6250 rows =
// 3.2 MB/table) fits the 4 MiB per-XCD L2, and the table-major block order
// keeps all resident blocks in the same table+range window, so gathers hit
// L2 instead of paying the L3/HBM round-trip every time.
#define T_TABLES 8
#define N_ROWS   100000
#define DIM      128
#define BAGS     16384
#define BAG_L    20
#define TOTAL_IDX (BAGS * BAG_L)
#define NPART    16
#define RANGE    ((N_ROWS + NPART - 1) / NPART)   // 6250 rows = 3.2 MB

#define DV (DIM / 4)   // float4 chunks per row = 32

typedef float nativef4 __attribute__((ext_vector_type(4)));

__global__ __launch_bounds__(256) void merged_embbag_kernel(
    const float4* __restrict__ weights,
    const int*    __restrict__ indices,
    const int*    __restrict__ offsets,
    float4*       __restrict__ out)
{
    int gid = blockIdx.x * blockDim.x + threadIdx.x;   // [0, T*B*DV)
    int c  = gid & (DV - 1);        // float4 column within row
    int tb = gid >> 5;              // table*B + bag  (DV == 32)
    int b  = tb & (BAGS - 1);
    int t  = tb >> 14;              // BAGS == 16384 == 2^14

    const int* off = offsets + t * BAGS;
    int start = off[b];
    int end   = (b == BAGS - 1) ? TOTAL_IDX : off[b + 1];
    int n = end - start;

    const int*    idx = indices + (size_t)t * TOTAL_IDX + start;
    const float4* w   = weights + (size_t)t * N_ROWS * DV + c;

    float4 acc = make_float4(0.f, 0.f, 0.f, 0.f);

    if (n == BAG_L) {
        int rows[BAG_L];
        #pragma unroll
        for (int j = 0; j < BAG_L; ++j) rows[j] = idx[j];

        // Sweep row ranges; within a range every active gather is an L2 hit
        // once any resident block has touched the line.
        for (int p = 0; p < NPART; ++p) {
            int lo = p * RANGE;
            #pragma unroll
            for (int j = 0; j < BAG_L; ++j) {
                if ((unsigned)(rows[j] - lo) < (unsigned)RANGE) {
                    float4 v = w[(size_t)rows[j] * DV];
                    acc.x += v.x; acc.y += v.y; acc.z += v.z; acc.w += v.w;
                }
            }
        }
    } else {
        // General fallback: arbitrary bag sizes (EmbeddingBag semantics).
        for (int p = 0; p < n; ++p) {
            int row = idx[p];
            float4 v = w[(size_t)row * DV];
            acc.x += v.x; acc.y += v.y; acc.z += v.z; acc.w += v.w;
        }
    }

    // Write-only stream: keep it out of L2 so it can't evict weight ranges.
    // (native clang vector type required by the nontemporal builtin)
    nativef4 accv = { acc.x, acc.y, acc.z, acc.w };
    __builtin_nontemporal_store(accv, (nativef4*)&out[gid]);
}

extern "C" void kernel_launch(void* const* d_in, const int* in_sizes, int n_in,
                              void* d_out, int out_size, void* d_ws, size_t ws_size,
                              hipStream_t stream) {
    const float4* weights = (const float4*)d_in[0];
    const int*    indices = (const int*)d_in[1];
    const int*    offsets = (const int*)d_in[2];
    float4*       out     = (float4*)d_out;

    const int total_threads = T_TABLES * BAGS * DV;   // 4,194,304
    const int block = 256;
    const int grid  = (total_threads + block - 1) / block;
    merged_embbag_kernel<<<grid, block, 0, stream>>>(weights, indices, offsets, out);
}